// Round 2
// baseline (134.026 us; speedup 1.0000x reference)
//
#include <hip/hip_runtime.h>
#include <math.h>

#define BATCH 8
#define NN 512
#define EMBED 128
#define EPAIRS (EMBED / 2)            // 64
#define NPOS (BATCH * NN * NN)        // 2,097,152
#define PPT 4                         // positions per thread
#define BLOCK 256
#define POS_PER_BLOCK (PPT * BLOCK)   // 1024
#define NBLOCKS (NPOS / POS_PER_BLOCK) // 2048  -> 8 blocks/CU, 32 waves/CU

// u = -x*log2(e); sigmoid(x) = rcp(1 + 2^u); silu(x) = (-ln2*u)*sigmoid.
#define NEG_LOG2E (-1.4426950408889634f)
#define NEG_LN2   (-0.6931471805599453f)

typedef __attribute__((ext_vector_type(2))) float v2f;

__global__ __launch_bounds__(BLOCK) void fused_neural_bias_kernel(
    const float* __restrict__ coords,   // [B, N, 2]
    const float* __restrict__ cost,     // [B, N, N]
    const float* __restrict__ dur,      // [B, N, N]
    const float* __restrict__ W1,       // [3, E]
    const float* __restrict__ b1,       // [E]
    const float* __restrict__ W2,       // [E, 1]
    const float* __restrict__ b2,       // [1]
    float* __restrict__ out)            // [B, N, N]
{
    // Per e-pair packed weights: wab = {wa0,wa1,wb0,wb1}, wcb = {wc0,wc1,b10,b11}
    __shared__ float4 wabS[EPAIRS];
    __shared__ float4 wcbS[EPAIRS];
    __shared__ float2 w2S[EPAIRS];

    const int tid = threadIdx.x;
    if (tid < EPAIRS) {
        int e0 = 2 * tid, e1 = 2 * tid + 1;
        wabS[tid] = make_float4(W1[e0] * NEG_LOG2E, W1[e1] * NEG_LOG2E,
                                W1[EMBED + e0] * NEG_LOG2E, W1[EMBED + e1] * NEG_LOG2E);
        wcbS[tid] = make_float4(W1[2*EMBED + e0] * NEG_LOG2E, W1[2*EMBED + e1] * NEG_LOG2E,
                                b1[e0] * NEG_LOG2E, b1[e1] * NEG_LOG2E);
        w2S[tid] = make_float2(W2[e0] * NEG_LN2, W2[e1] * NEG_LN2);
    }
    __syncthreads();

    const float bias2 = b2[0];
    const int base = blockIdx.x * POS_PER_BLOCK + tid;

    float ang[PPT], cs[PPT], du[PPT];
    v2f acc[PPT];

    const float2* c2 = (const float2*)coords;
    #pragma unroll
    for (int k = 0; k < PPT; k++) {
        int pos = base + k * BLOCK;          // coalesced per wave
        int b   = pos >> 18;                 // / (512*512)
        int rem = pos & (NN * NN - 1);
        int i   = rem >> 9;                  // / 512
        int j   = rem & (NN - 1);
        float2 ci = c2[b * NN + i];
        float2 cj = c2[b * NN + j];
        ang[k] = atan2f(ci.y - cj.y, ci.x - cj.x);
        cs[k]  = cost[pos];
        du[k]  = dur[pos];
        acc[k] = (v2f){0.0f, 0.0f};
    }

    #pragma unroll 2
    for (int ep = 0; ep < EPAIRS; ep++) {
        float4 wab = wabS[ep];
        float4 wcb = wcbS[ep];
        float2 w2p = w2S[ep];
        v2f wa = (v2f){wab.x, wab.y};
        v2f wb = (v2f){wab.z, wab.w};
        v2f wc = (v2f){wcb.x, wcb.y};
        v2f bb = (v2f){wcb.z, wcb.w};
        v2f w2 = (v2f){w2p.x, w2p.y};

        #pragma unroll
        for (int k = 0; k < PPT; k++) {
            v2f a2 = (v2f){ang[k], ang[k]};
            v2f c_ = (v2f){cs[k], cs[k]};
            v2f d_ = (v2f){du[k], du[k]};
            // u = -log2e * (angle*wa + cost*wb + dur*wc + b1)   (3x v_pk_fma_f32)
            v2f u = __builtin_elementwise_fma(a2, wa,
                    __builtin_elementwise_fma(c_, wb,
                    __builtin_elementwise_fma(d_, wc, bb)));
            v2f p;
            p.x = __builtin_amdgcn_exp2f(u.x);        // v_exp_f32
            p.y = __builtin_amdgcn_exp2f(u.y);
            v2f s = p + (v2f){1.0f, 1.0f};            // v_pk_add_f32
            v2f r;
            r.x = __builtin_amdgcn_rcpf(s.x);         // v_rcp_f32 = sigmoid
            r.y = __builtin_amdgcn_rcpf(s.y);
            // acc += w2 * (u * sigmoid)              (v_pk_mul + v_pk_fma)
            acc[k] = __builtin_elementwise_fma(u * r, w2, acc[k]);
        }
    }

    #pragma unroll
    for (int k = 0; k < PPT; k++) {
        out[base + k * BLOCK] = acc[k].x + acc[k].y + bias2;
    }
}

extern "C" void kernel_launch(void* const* d_in, const int* in_sizes, int n_in,
                              void* d_out, int out_size, void* d_ws, size_t ws_size,
                              hipStream_t stream) {
    const float* coords = (const float*)d_in[0];
    const float* cost   = (const float*)d_in[1];
    const float* dur    = (const float*)d_in[2];
    const float* W1     = (const float*)d_in[3];
    const float* b1     = (const float*)d_in[4];
    const float* W2     = (const float*)d_in[5];
    const float* b2     = (const float*)d_in[6];
    float* out = (float*)d_out;

    fused_neural_bias_kernel<<<NBLOCKS, BLOCK, 0, stream>>>(
        coords, cost, dur, W1, b1, W2, b2, out);
}

// Round 3
// 90.630 us; speedup vs baseline: 1.4788x; 1.4788x over previous
//
#include <hip/hip_runtime.h>
#include <math.h>

#define BATCH 8
#define NN 512
#define EMBED 128
#define NPOS (BATCH * NN * NN)        // 2,097,152

// u = -x*log2(e); sigmoid(x) = rcp(1 + 2^u); silu(x) = (-ln2*u)*sigmoid.
#define NEG_LOG2E (-1.4426950408889634f)
#define NEG_LN2   (-0.6931471805599453f)
#define PI_F      3.14159265358979323846f

// LUT geometry: F(angle, cost, dur) sampled on [-pi,pi] x [0,1] x [0,1]
#define LA 49                   // 48 angle intervals
#define LC 17                   // 16 cost intervals
#define LD 17                   // 16 dur intervals
#define LUT_N   (LA * LC * LD)  // 14161 floats = 56,644 B
#define LUT_PAD 14164           // multiple of 4 for float4 staging
#define STRIDE_C LA             // 49
#define STRIDE_D (LA * LC)      // 833

// ---------------- Kernel 1: build the LUT (exact MLP at grid points) --------
__global__ __launch_bounds__(256) void build_lut_kernel(
    const float* __restrict__ W1, const float* __restrict__ b1,
    const float* __restrict__ W2, const float* __restrict__ b2,
    float* __restrict__ lut)
{
    __shared__ float4 wpk[EMBED];   // (wa, wb, wc, b1) * -log2(e)
    __shared__ float  w2s[EMBED];   // W2 * -ln2
    const int tid = threadIdx.x;
    if (tid < EMBED) {
        wpk[tid] = make_float4(W1[tid] * NEG_LOG2E, W1[EMBED + tid] * NEG_LOG2E,
                               W1[2*EMBED + tid] * NEG_LOG2E, b1[tid] * NEG_LOG2E);
        w2s[tid] = W2[tid] * NEG_LN2;
    }
    __syncthreads();

    const int n = blockIdx.x * 256 + tid;
    if (n >= LUT_N) return;
    const int ia  = n % LA;
    const int rem = n / LA;
    const int ic  = rem % LC;
    const int idd = rem / LC;
    const float a = __builtin_fmaf((float)ia, PI_F / 24.0f, -PI_F);
    const float c = (float)ic  * (1.0f / 16.0f);
    const float d = (float)idd * (1.0f / 16.0f);

    float acc = b2[0];
    #pragma unroll 4
    for (int e = 0; e < EMBED; e++) {
        float4 w = wpk[e];
        float u = __builtin_fmaf(a, w.x,
                  __builtin_fmaf(c, w.y,
                  __builtin_fmaf(d, w.z, w.w)));
        float p = __builtin_amdgcn_exp2f(u);
        float r = __builtin_amdgcn_rcpf(1.0f + p);
        acc = __builtin_fmaf(u * r, w2s[e], acc);
    }
    lut[n] = acc;
}

// ---------------- Kernel 2: trilinear-interp apply --------------------------
__global__ __launch_bounds__(256) void apply_lut_kernel(
    const float* __restrict__ coords, const float* __restrict__ cost,
    const float* __restrict__ dur, const float* __restrict__ lutG,
    float* __restrict__ out)
{
    __shared__ float lut[LUT_PAD];
    {
        const float4* s4 = (const float4*)lutG;
        float4* d4 = (float4*)lut;
        #pragma unroll 2
        for (int i = threadIdx.x; i < LUT_PAD / 4; i += 256) d4[i] = s4[i];
    }
    __syncthreads();

    // 8 consecutive positions per thread; block covers 2048 consecutive.
    // Rows are 512 wide -> a thread's 8 positions never cross a row.
    const int start = blockIdx.x * 2048 + threadIdx.x * 8;
    const int b   = start >> 18;
    const int rem = start & (NN * NN - 1);
    const int i   = rem >> 9;
    const int j0  = rem & (NN - 1);

    const float2* c2 = (const float2*)coords;
    const float2 ci = c2[b * NN + i];
    const float4* cj4 = (const float4*)(c2 + b * NN + j0);   // 64B-aligned
    float4 q0 = cj4[0], q1 = cj4[1], q2 = cj4[2], q3 = cj4[3];
    const float cjx[8] = {q0.x, q0.z, q1.x, q1.z, q2.x, q2.z, q3.x, q3.z};
    const float cjy[8] = {q0.y, q0.w, q1.y, q1.w, q2.y, q2.w, q3.y, q3.w};

    const float4* cs4 = (const float4*)(cost + start);
    const float4* du4 = (const float4*)(dur + start);
    float4 cA = cs4[0], cB = cs4[1];
    float4 dA = du4[0], dB = du4[1];
    const float cs[8] = {cA.x, cA.y, cA.z, cA.w, cB.x, cB.y, cB.z, cB.w};
    const float dd[8] = {dA.x, dA.y, dA.z, dA.w, dB.x, dB.y, dB.z, dB.w};

    float res[8];
    #pragma unroll
    for (int k = 0; k < 8; k++) {
        float ang = atan2f(ci.y - cjy[k], ci.x - cjx[k]);   // [-pi, pi]; (0,0)->0
        // angle index: s in [0,48]; (int) truncation handles tiny negatives
        float s = __builtin_fmaf(ang, 24.0f / PI_F, 24.0f);
        int ia = (int)s; ia = ia < 47 ? ia : 47;
        float fa = s - (float)ia;
        float tc = cs[k] * 16.0f;
        int ic = (int)tc; ic = ic < 15 ? ic : 15;
        float fc = tc - (float)ic;
        float td = dd[k] * 16.0f;
        int idd = (int)td; idd = idd < 15 ? idd : 15;
        float fd = td - (float)idd;

        const float* p = &lut[idd * STRIDE_D + ic * STRIDE_C + ia];
        float v000 = p[0],              v100 = p[1];
        float v010 = p[STRIDE_C],       v110 = p[STRIDE_C + 1];
        float v001 = p[STRIDE_D],       v101 = p[STRIDE_D + 1];
        float v011 = p[STRIDE_D + STRIDE_C], v111 = p[STRIDE_D + STRIDE_C + 1];

        float x00 = __builtin_fmaf(fa, v100 - v000, v000);
        float x10 = __builtin_fmaf(fa, v110 - v010, v010);
        float x01 = __builtin_fmaf(fa, v101 - v001, v001);
        float x11 = __builtin_fmaf(fa, v111 - v011, v011);
        float y0  = __builtin_fmaf(fc, x10 - x00, x00);
        float y1  = __builtin_fmaf(fc, x11 - x01, x01);
        res[k]    = __builtin_fmaf(fd, y1 - y0, y0);
    }

    float4* o4 = (float4*)(out + start);
    o4[0] = make_float4(res[0], res[1], res[2], res[3]);
    o4[1] = make_float4(res[4], res[5], res[6], res[7]);
}

// ---------------- Fallback: exact kernel (round-2), used if ws too small ----
#define FB_PPT 4
#define FB_POS_PER_BLOCK (FB_PPT * 256)
__global__ __launch_bounds__(256) void exact_kernel(
    const float* __restrict__ coords, const float* __restrict__ cost,
    const float* __restrict__ dur, const float* __restrict__ W1,
    const float* __restrict__ b1, const float* __restrict__ W2,
    const float* __restrict__ b2, float* __restrict__ out)
{
    __shared__ float4 wpk[EMBED];
    __shared__ float  w2s[EMBED];
    const int tid = threadIdx.x;
    if (tid < EMBED) {
        wpk[tid] = make_float4(W1[tid] * NEG_LOG2E, W1[EMBED + tid] * NEG_LOG2E,
                               W1[2*EMBED + tid] * NEG_LOG2E, b1[tid] * NEG_LOG2E);
        w2s[tid] = W2[tid] * NEG_LN2;
    }
    __syncthreads();
    const float bias2 = b2[0];
    const int base = blockIdx.x * FB_POS_PER_BLOCK + tid;
    float ang[FB_PPT], cs[FB_PPT], du[FB_PPT], acc[FB_PPT];
    const float2* c2 = (const float2*)coords;
    #pragma unroll
    for (int k = 0; k < FB_PPT; k++) {
        int pos = base + k * 256;
        int b = pos >> 18, rem = pos & (NN*NN - 1);
        int i = rem >> 9, j = rem & (NN - 1);
        float2 ci = c2[b * NN + i];
        float2 cj = c2[b * NN + j];
        ang[k] = atan2f(ci.y - cj.y, ci.x - cj.x);
        cs[k] = cost[pos]; du[k] = dur[pos]; acc[k] = bias2;
    }
    #pragma unroll 4
    for (int e = 0; e < EMBED; e++) {
        float4 w = wpk[e]; float w2 = w2s[e];
        #pragma unroll
        for (int k = 0; k < FB_PPT; k++) {
            float u = __builtin_fmaf(ang[k], w.x,
                      __builtin_fmaf(cs[k], w.y,
                      __builtin_fmaf(du[k], w.z, w.w)));
            float p = __builtin_amdgcn_exp2f(u);
            float r = __builtin_amdgcn_rcpf(1.0f + p);
            acc[k] = __builtin_fmaf(u * r, w2, acc[k]);
        }
    }
    #pragma unroll
    for (int k = 0; k < FB_PPT; k++) out[base + k * 256] = acc[k];
}

extern "C" void kernel_launch(void* const* d_in, const int* in_sizes, int n_in,
                              void* d_out, int out_size, void* d_ws, size_t ws_size,
                              hipStream_t stream) {
    const float* coords = (const float*)d_in[0];
    const float* cost   = (const float*)d_in[1];
    const float* dur    = (const float*)d_in[2];
    const float* W1     = (const float*)d_in[3];
    const float* b1     = (const float*)d_in[4];
    const float* W2     = (const float*)d_in[5];
    const float* b2     = (const float*)d_in[6];
    float* out = (float*)d_out;

    if (ws_size >= (size_t)LUT_PAD * sizeof(float)) {
        float* lut = (float*)d_ws;
        build_lut_kernel<<<(LUT_N + 255) / 256, 256, 0, stream>>>(W1, b1, W2, b2, lut);
        apply_lut_kernel<<<NPOS / 2048, 256, 0, stream>>>(coords, cost, dur, lut, out);
    } else {
        exact_kernel<<<NPOS / FB_POS_PER_BLOCK, 256, 0, stream>>>(
            coords, cost, dur, W1, b1, W2, b2, out);
    }
}